// Round 13
// baseline (4435.893 us; speedup 1.0000x reference)
//
#include <hip/hip_runtime.h>
#include <hip/hip_bf16.h>
#include <cstdint>
#include <cstddef>

// Problem constants
#define L_SEQ   4096
#define BATCH_N 16
#define BLTOK   (BATCH_N * L_SEQ)   // 65536 tokens
#define DMODEL  128
#define DINNER  256
#define DSTATE  32
#define DTRANK  8

// Scan chunking
#define LC  64                      // chunk length
#define GCH 64                      // chunks per sequence
#define LOG2E 1.44269504088896340736f

typedef _Float16 half8 __attribute__((ext_vector_type(8)));
typedef float    floatx4 __attribute__((ext_vector_type(4)));

#define LDSW 40   // LDS row stride in halves (32 data + 8 pad; 80B = 16B-aligned, 2-way banks = free)

// ---------------------------------------------------------------------------
// Pre-conv (1->128 channels, k=7, same padding) + exact GELU.  Writes fp32 + fp16.
// ---------------------------------------------------------------------------
__global__ __launch_bounds__(128) void pre_conv_gelu(
    const float* __restrict__ x,      // (16,4096,1)
    const float* __restrict__ w,      // (128,1,7)
    const float* __restrict__ bias,   // (128,)
    float* __restrict__ h,            // (BLTOK,128)
    _Float16* __restrict__ hb)        // (BLTOK,128)
{
    int r = blockIdx.x;
    int c = threadIdx.x;
    int b = r >> 12;
    int l = r & 4095;
    float acc = bias[c];
    const float* wp = w + c * 7;
#pragma unroll
    for (int k = 0; k < 7; ++k) {
        int ll = l + k - 3;
        if (ll >= 0 && ll < L_SEQ)
            acc += x[(size_t)(b << 12) + ll] * wp[k];
    }
    float ge = 0.5f * acc * (1.f + erff(acc * 0.70710678118654752f));
    h[(size_t)r * DMODEL + c]  = ge;
    hb[(size_t)r * DMODEL + c] = (_Float16)ge;
}

// ---------------------------------------------------------------------------
// Convert fp32 weights -> fp16 (runs once per launch; deterministic).
// ---------------------------------------------------------------------------
__global__ __launch_bounds__(256) void cvt_weights(
    const float* __restrict__ inw,  _Float16* __restrict__ inwh,   // 12*512*128
    const float* __restrict__ xpw,  _Float16* __restrict__ xpwh,   // 12*72*256
    const float* __restrict__ outw, _Float16* __restrict__ outwh)  // 12*128*256
{
    int i = blockIdx.x * 256 + threadIdx.x;
    if (i < 12 * 512 * 128) inwh[i]  = (_Float16)inw[i];
    if (i < 12 * 72 * 256)  xpwh[i]  = (_Float16)xpw[i];
    if (i < 12 * 128 * 256) outwh[i] = (_Float16)outw[i];
}

// ---------------------------------------------------------------------------
// MFMA fp16 GEMM: C[M,N] = A[M,K] @ W[N,K]^T, fp32 accumulate.
// 64x64 tile, 256 threads = 4 waves; wave w computes rows 16w..16w+15 x all
// 64 cols via 4 mfma_f32_16x16x32_f16.  K multiple of 32.
// rev!=0: A rows read per-batch flipped (L=4096).
// Epilogue modes:
//   0: x_proj  -> Out[row*72+col] fp32, col<N guarded
//   1: in_proj -> col<256: U16[row*256+col] fp16 (u); col>=256: Zb bf16 (z)
//   2: out_proj fwd -> U16[row*128+col] fp16 (E)
//   3: out_proj bwd -> U16[flip(row)*128+col] = 0.5*(existing + acc), fp16
// ---------------------------------------------------------------------------
__global__ __launch_bounds__(256) void gemm_mfma(
    const _Float16* __restrict__ A, int lda,
    const _Float16* __restrict__ W, int ldw,   // N x ldw, K contiguous
    float* __restrict__ Out,
    _Float16* __restrict__ U16,
    __hip_bfloat16* __restrict__ Zb,
    int N, int K, int rev, int mode)
{
    __shared__ __align__(16) _Float16 As[64 * LDSW];
    __shared__ __align__(16) _Float16 Ws[64 * LDSW];

    int tid  = threadIdx.x;
    int wave = tid >> 6;
    int lane = tid & 63;
    int m0 = blockIdx.y * 64;
    int n0 = blockIdx.x * 64;

    // staging: thread t loads 16B of row (t>>2), k-chunk (t&3)*8
    int srow = tid >> 2;
    int skc  = (tid & 3) * 8;

    int garow = m0 + srow;
    if (rev) { int bb = garow >> 12; int ll = garow & 4095; garow = (bb << 12) + (4095 - ll); }
    const _Float16* Aptr = A + (size_t)garow * lda + skc;
    int wrow = n0 + srow;
    bool wok = (wrow < N);
    const _Float16* Wptr = W + (size_t)(wok ? wrow : 0) * ldw + skc;

    int lr = lane & 15;          // m (A) / n (B) / col (C)
    int lk = (lane >> 4) * 8;    // k offset within 32
    int soff = srow * LDSW + skc;
    int aoff = (16 * wave + lr) * LDSW + lk;

    floatx4 acc0 = {0.f, 0.f, 0.f, 0.f};
    floatx4 acc1 = acc0, acc2 = acc0, acc3 = acc0;

    for (int k0 = 0; k0 < K; k0 += 32) {
        half8 av = *(const half8*)(Aptr + k0);
        half8 bv = {};
        if (wok) bv = *(const half8*)(Wptr + k0);
        __syncthreads();
        *(half8*)&As[soff] = av;
        *(half8*)&Ws[soff] = bv;
        __syncthreads();
        half8 af = *(const half8*)&As[aoff];
        half8 b0 = *(const half8*)&Ws[( 0 + lr) * LDSW + lk];
        half8 b1 = *(const half8*)&Ws[(16 + lr) * LDSW + lk];
        half8 b2 = *(const half8*)&Ws[(32 + lr) * LDSW + lk];
        half8 b3 = *(const half8*)&Ws[(48 + lr) * LDSW + lk];
        acc0 = __builtin_amdgcn_mfma_f32_16x16x32_f16(af, b0, acc0, 0, 0, 0);
        acc1 = __builtin_amdgcn_mfma_f32_16x16x32_f16(af, b1, acc1, 0, 0, 0);
        acc2 = __builtin_amdgcn_mfma_f32_16x16x32_f16(af, b2, acc2, 0, 0, 0);
        acc3 = __builtin_amdgcn_mfma_f32_16x16x32_f16(af, b3, acc3, 0, 0, 0);
    }

    // C/D layout: col = lane&15, row = (lane>>4)*4 + reg
    int orow = m0 + 16 * wave + (lane >> 4) * 4;
    floatx4 av4[4] = {acc0, acc1, acc2, acc3};
#pragma unroll
    for (int jb = 0; jb < 4; ++jb) {
        int col = n0 + jb * 16 + lr;
#pragma unroll
        for (int r = 0; r < 4; ++r) {
            int row = orow + r;
            float v = av4[jb][r];
            if (mode == 0) {
                if (col < N) Out[(size_t)row * 72 + col] = v;
            } else if (mode == 1) {
                if (col < 256) U16[(size_t)row * 256 + col] = (_Float16)v;
                else Zb[(size_t)row * 256 + (col - 256)] = __float2bfloat16(v);
            } else if (mode == 2) {
                U16[(size_t)row * 128 + col] = (_Float16)v;
            } else {
                int bb = row >> 12, ll = row & 4095;
                size_t o = ((size_t)(bb << 12) + (4095 - ll)) * 128 + col;
                U16[o] = (_Float16)(0.5f * ((float)U16[o] + v));
            }
        }
    }
}

// ---------------------------------------------------------------------------
// Depthwise causal conv (k=8, pad (7,0)) + SiLU, register sliding window.
// Reads u fp16 (stride 256), writes uc fp16.
// ---------------------------------------------------------------------------
__global__ __launch_bounds__(256) void dwconv_silu(
    const _Float16* __restrict__ u,   // (BLTOK,256)
    const float* __restrict__ cw,     // (256,1,8)
    const float* __restrict__ cb,     // (256,)
    _Float16* __restrict__ uc)        // (BLTOK,256)
{
    int b  = blockIdx.x >> 7;
    int lt = blockIdx.x & 127;
    int l0 = lt * 32;
    int d  = threadIdx.x;

    float wv[8];
    const float* wp = cw + d * 8;
#pragma unroll
    for (int k = 0; k < 8; ++k) wv[k] = wp[k];
    float bias = cb[d];

    size_t rowb = (size_t)(b << 12);
    float win[8];
#pragma unroll
    for (int j = 0; j < 7; ++j) {
        int ll = l0 - 7 + j;
        win[j] = (ll >= 0) ? (float)u[(rowb + ll) * DINNER + d] : 0.f;
    }
#pragma unroll
    for (int i = 0; i < 32; ++i) {
        int l = l0 + i;
        win[7] = (float)u[(rowb + l) * DINNER + d];
        float acc = bias;
#pragma unroll
        for (int j = 0; j < 8; ++j) acc += win[j] * wv[j];
        float s = acc / (1.f + __expf(-acc));
        uc[(rowb + l) * DINNER + d] = (_Float16)s;
#pragma unroll
        for (int j = 0; j < 7; ++j) win[j] = win[j + 1];
    }
}

// ---------------------------------------------------------------------------
// Chunked selective scan, lane = channel d, h[32] states in SCALAR registers
// (gfx950: scalar per-thread arrays get AGPR backing — R7/R9 measured clean
// at VGPR=56 / 93MB traffic; R8's f32x2 vector arrays and R10's prefetch
// temps both spilled to scratch.  Keep arrays scalar!)
// R13: the per-t u global load sat on the critical path (du feeds all 32
// h-updates; ucb is 33MB -> HBM latency each t).  Stage the chunk's u slab
// (64 tokens x 256 d fp16 = 32KB, contiguous) into LDS once — zero extra
// VGPRs, LDS/block 50.4KB -> 3 blocks/CU (same ~12 waves/CU residency).
// Phase 1: zero-init local scan -> h_end[32], S = sum(dt).
// ---------------------------------------------------------------------------
__global__ __launch_bounds__(256, 4) void scan_phase1(
    const float* __restrict__ dbc,    // (BLTOK,72)
    const _Float16* __restrict__ u,   // (BLTOK,256)
    float* __restrict__ aggh,
    float* __restrict__ aggs,
    const float* __restrict__ dt_w,
    const float* __restrict__ dt_b,
    const float* __restrict__ a_log)
{
    __shared__ __align__(16) float sh[LC * 72];
    __shared__ __align__(16) _Float16 us[LC * 256];
    int bg = blockIdx.x;
    int b  = bg >> 6;
    int g  = bg & (GCH - 1);
    int d  = threadIdx.x;

    size_t base = (size_t)b * L_SEQ + (size_t)g * LC;
    {
        const float4* src4 = (const float4*)(dbc + base * 72);
        float4* dst4 = (float4*)sh;
        for (int i = d; i < LC * 18; i += 256) dst4[i] = src4[i];
        const float4* srcu = (const float4*)(u + base * 256);   // 16B = 8 halves
        float4* dstu = (float4*)us;
        for (int i = d; i < LC * 32; i += 256) dstu[i] = srcu[i];
    }

    const float* wr = dt_w + d * DTRANK;
    float w0 = wr[0], w1 = wr[1], w2 = wr[2], w3 = wr[3];
    float w4 = wr[4], w5 = wr[5], w6 = wr[6], w7 = wr[7];
    float bias = dt_b[d];

    float al2[32];
    {
        const float4* ar = (const float4*)(a_log + d * DSTATE);
#pragma unroll
        for (int k = 0; k < 8; ++k) {
            float4 v = ar[k];
            al2[4 * k + 0] = -__expf(v.x) * LOG2E;
            al2[4 * k + 1] = -__expf(v.y) * LOG2E;
            al2[4 * k + 2] = -__expf(v.z) * LOG2E;
            al2[4 * k + 3] = -__expf(v.w) * LOG2E;
        }
    }
    __syncthreads();

    float h[32];
#pragma unroll
    for (int n = 0; n < 32; ++n) h[n] = 0.f;
    float S = 0.f;

    for (int t = 0; t < LC; ++t) {
        const float* row = sh + t * 72;
        float4 r0 = *(const float4*)row;
        float4 r1 = *(const float4*)(row + 4);
        float dtr = bias + r0.x * w0 + r0.y * w1 + r0.z * w2 + r0.w * w3
                         + r1.x * w4 + r1.y * w5 + r1.z * w6 + r1.w * w7;
        float dtv = (dtr > 15.f) ? dtr : __logf(1.f + __expf(dtr));
        S += dtv;
        float du = dtv * (float)us[t * 256 + d];
#pragma unroll
        for (int n = 0; n < 32; n += 4) {
            float4 Bv = *(const float4*)(row + 8 + n);
            h[n + 0] = h[n + 0] * __builtin_amdgcn_exp2f(dtv * al2[n + 0]) + du * Bv.x;
            h[n + 1] = h[n + 1] * __builtin_amdgcn_exp2f(dtv * al2[n + 1]) + du * Bv.y;
            h[n + 2] = h[n + 2] * __builtin_amdgcn_exp2f(dtv * al2[n + 2]) + du * Bv.z;
            h[n + 3] = h[n + 3] * __builtin_amdgcn_exp2f(dtv * al2[n + 3]) + du * Bv.w;
        }
    }

    size_t ob = ((size_t)(b * GCH + g) * 32) * 256 + d;
#pragma unroll
    for (int n = 0; n < 32; ++n) aggh[ob + (size_t)n * 256] = h[n];
    aggs[(size_t)(b * GCH + g) * 256 + d] = S;
}

// ---------------------------------------------------------------------------
// Phase 2: serial combine across chunks.  P_n = exp(a_n * S_g).
// ---------------------------------------------------------------------------
__global__ __launch_bounds__(256) void scan_phase2(
    float* __restrict__ aggh,
    const float* __restrict__ aggs,
    const float* __restrict__ a_log)
{
    int b = blockIdx.x >> 5;
    int n = blockIdx.x & 31;
    int d = threadIdx.x;

    float a = -__expf(a_log[d * DSTATE + n]);
    float hrun = 0.f;
    for (int g = 0; g < GCH; ++g) {
        size_t os = (size_t)(b * GCH + g) * 256 + d;
        size_t oh = ((size_t)(b * GCH + g) * 32 + n) * 256 + d;
        float S  = aggs[os];
        float he = aggh[oh];
        aggh[oh] = hrun;
        hrun = hrun * __expf(a * S) + he;
    }
}

// ---------------------------------------------------------------------------
// Phase 3: local scan seeded with h_in; fused y = <h,C>, D skip, silu(z).
// u staged in LDS (critical-path load); z stays global — it's consumed late
// in the iteration (gate+store only) so its latency is hidden behind the
// ~500-cycle loop body.  z/y same buffer via two __restrict__ pointers.
// ---------------------------------------------------------------------------
__global__ __launch_bounds__(256, 4) void scan_phase3(
    const float* __restrict__ dbc,       // (BLTOK,72)
    const _Float16* __restrict__ u,      // (BLTOK,256)
    const __hip_bfloat16* __restrict__ z_in,  // (BLTOK,256) z gate
    _Float16* __restrict__ y_out,        // (BLTOK,256) y (same buffer as z_in)
    const float* __restrict__ aggh,
    const float* __restrict__ dt_w,
    const float* __restrict__ dt_b,
    const float* __restrict__ a_log,
    const float* __restrict__ Dp)
{
    __shared__ __align__(16) float sh[LC * 72];
    __shared__ __align__(16) _Float16 us[LC * 256];
    int bg = blockIdx.x;
    int b  = bg >> 6;
    int g  = bg & (GCH - 1);
    int d  = threadIdx.x;

    size_t base = (size_t)b * L_SEQ + (size_t)g * LC;
    {
        const float4* src4 = (const float4*)(dbc + base * 72);
        float4* dst4 = (float4*)sh;
        for (int i = d; i < LC * 18; i += 256) dst4[i] = src4[i];
        const float4* srcu = (const float4*)(u + base * 256);
        float4* dstu = (float4*)us;
        for (int i = d; i < LC * 32; i += 256) dstu[i] = srcu[i];
    }

    const float* wr = dt_w + d * DTRANK;
    float w0 = wr[0], w1 = wr[1], w2 = wr[2], w3 = wr[3];
    float w4 = wr[4], w5 = wr[5], w6 = wr[6], w7 = wr[7];
    float bias = dt_b[d];
    float Dd = Dp[d];

    float al2[32];
    {
        const float4* ar = (const float4*)(a_log + d * DSTATE);
#pragma unroll
        for (int k = 0; k < 8; ++k) {
            float4 v = ar[k];
            al2[4 * k + 0] = -__expf(v.x) * LOG2E;
            al2[4 * k + 1] = -__expf(v.y) * LOG2E;
            al2[4 * k + 2] = -__expf(v.z) * LOG2E;
            al2[4 * k + 3] = -__expf(v.w) * LOG2E;
        }
    }

    float h[32];
    size_t ob = ((size_t)(b * GCH + g) * 32) * 256 + d;
#pragma unroll
    for (int n = 0; n < 32; ++n) h[n] = aggh[ob + (size_t)n * 256];

    __syncthreads();

    for (int t = 0; t < LC; ++t) {
        const float* row = sh + t * 72;
        float4 r0 = *(const float4*)row;
        float4 r1 = *(const float4*)(row + 4);
        float dtr = bias + r0.x * w0 + r0.y * w1 + r0.z * w2 + r0.w * w3
                         + r1.x * w4 + r1.y * w5 + r1.z * w6 + r1.w * w7;
        float dtv = (dtr > 15.f) ? dtr : __logf(1.f + __expf(dtr));
        float uv = (float)us[t * 256 + d];
        float du = dtv * uv;
        float zv = __bfloat162float(z_in[(base + t) * DINNER + d]);

        float y = 0.f;
#pragma unroll
        for (int n = 0; n < 32; n += 4) {
            float4 Bv = *(const float4*)(row + 8 + n);
            float4 Cv = *(const float4*)(row + 40 + n);
            h[n + 0] = h[n + 0] * __builtin_amdgcn_exp2f(dtv * al2[n + 0]) + du * Bv.x;
            h[n + 1] = h[n + 1] * __builtin_amdgcn_exp2f(dtv * al2[n + 1]) + du * Bv.y;
            h[n + 2] = h[n + 2] * __builtin_amdgcn_exp2f(dtv * al2[n + 2]) + du * Bv.z;
            h[n + 3] = h[n + 3] * __builtin_amdgcn_exp2f(dtv * al2[n + 3]) + du * Bv.w;
            y += h[n + 0] * Cv.x + h[n + 1] * Cv.y
               + h[n + 2] * Cv.z + h[n + 3] * Cv.w;
        }
        float yv = y + uv * Dd;
        float sig = 1.f / (1.f + __expf(-zv));
        y_out[(base + t) * DINNER + d] = (_Float16)(yv * (zv * sig));
    }
}

// ---------------------------------------------------------------------------
// h = LayerNorm(osum + h); osum is fp16 (E diet).  Writes fp32 h and fp16 hb.
// ---------------------------------------------------------------------------
__global__ __launch_bounds__(128) void combine_ln(
    const _Float16* __restrict__ osum, // (BLTOK,128)
    float* __restrict__ h,             // (BLTOK,128)
    _Float16* __restrict__ hb,         // (BLTOK,128)
    const float* __restrict__ g,
    const float* __restrict__ be)
{
    __shared__ float red[128];
    int r = blockIdx.x;
    int c = threadIdx.x;
    size_t idx = (size_t)r * DMODEL + c;

    float v = (float)osum[idx] + h[idx];

    red[c] = v;
    __syncthreads();
    for (int s = 64; s > 0; s >>= 1) {
        if (c < s) red[c] += red[c + s];
        __syncthreads();
    }
    float mu = red[0] * (1.f / 128.f);
    __syncthreads();
    float dv = v - mu;
    red[c] = dv * dv;
    __syncthreads();
    for (int s = 64; s > 0; s >>= 1) {
        if (c < s) red[c] += red[c + s];
        __syncthreads();
    }
    float var = red[0] * (1.f / 128.f);
    float o = dv * rsqrtf(var + 1e-5f) * g[c] + be[c];
    h[idx]  = o;
    hb[idx] = (_Float16)o;
}

// ---------------------------------------------------------------------------
__global__ __launch_bounds__(128) void final_proj(
    const float* __restrict__ h,
    const float* __restrict__ pw,     // (1,128)
    const float* __restrict__ pb,     // (1,)
    float* __restrict__ out)          // (BLTOK,)
{
    __shared__ float red[128];
    int r = blockIdx.x;
    int c = threadIdx.x;
    red[c] = h[(size_t)r * DMODEL + c] * pw[c];
    __syncthreads();
    for (int s = 64; s > 0; s >>= 1) {
        if (c < s) red[c] += red[c + s];
        __syncthreads();
    }
    if (c == 0) out[r] = red[0] + pb[0];
}

// ---------------------------------------------------------------------------
extern "C" void kernel_launch(void* const* d_in, const int* in_sizes, int n_in,
                              void* d_out, int out_size, void* d_ws, size_t ws_size,
                              hipStream_t stream)
{
    const float* x    = (const float*)d_in[0];
    const float* pcw  = (const float*)d_in[1];
    const float* pcb  = (const float*)d_in[2];
    const float* inw  = (const float*)d_in[3];
    const float* cw   = (const float*)d_in[4];
    const float* cb   = (const float*)d_in[5];
    const float* xpw  = (const float*)d_in[6];
    const float* dtw  = (const float*)d_in[7];
    const float* dtb  = (const float*)d_in[8];
    const float* alog = (const float*)d_in[9];
    const float* dpar = (const float*)d_in[10];
    const float* outw = (const float*)d_in[11];
    const float* lng  = (const float*)d_in[12];
    const float* lnb  = (const float*)d_in[13];
    const float* pw   = (const float*)d_in[14];
    const float* pb   = (const float*)d_in[15];
    float* out = (float*)d_out;

    // Workspace layout (~200 MiB, lifetime-aliased):
    //   h    : BLTOK*128 f32   residual stream
    //   A    : BLTOK*256 f32   front half: u16 fp16 (in_proj->conv) then
    //                          dbc fp32 72-col (x_proj->scan) [disjoint lifetimes];
    //                          back half (offset BLTOK*128 f32): aggh
    //   zy   : BLTOK*256 2B    z bf16 (in_proj) -> y fp16 (scan, in-place)
    //   ucb  : BLTOK*256 f16   conv output (scan input)
    //   hb   : BLTOK*128 f16   fp16 shadow of h (GEMM input)
    //   E16  : BLTOK*128 f16   0.5*(fwd + flip(bwd)) accumulation (fp16 diet)
    //   w16  : fp16 weights (inwh | xpwh | outwh) | aggs f32
    float* h  = (float*)d_ws;
    float* A  = h + (size_t)BLTOK * 128;
    __hip_bfloat16* zy = (__hip_bfloat16*)(A + (size_t)BLTOK * 256);
    _Float16* ucb = (_Float16*)((char*)zy + (size_t)BLTOK * 256 * 2);
    _Float16* hb  = (_Float16*)((char*)ucb + (size_t)BLTOK * 256 * 2);
    _Float16* E16 = (_Float16*)((char*)hb + (size_t)BLTOK * 128 * 2);
    _Float16* inwh  = E16 + (size_t)BLTOK * 128;
    _Float16* xpwh  = inwh + (size_t)12 * 512 * 128;
    _Float16* outwh = xpwh + (size_t)12 * 72 * 256;
    float* aggs = (float*)(outwh + (size_t)12 * 128 * 256);   // 16*GCH*256 f32 (1MB)
    _Float16* u16 = (_Float16*)A;                             // aliases dbc (disjoint lifetime)
    float* dbc  = A;                                          // 72-col compact fp32
    float* aggh = A + (size_t)BLTOK * 128;                    // 16*GCH*32*256 f32 (exact fit)

    cvt_weights<<<(12 * 512 * 128 + 255) / 256, 256, 0, stream>>>(
        inw, inwh, xpw, xpwh, outw, outwh);
    pre_conv_gelu<<<BLTOK, 128, 0, stream>>>(x, pcw, pcb, h, hb);

    for (int blk = 0; blk < 6; ++blk) {
        for (int dir = 0; dir < 2; ++dir) {
            int s = blk * 2 + dir;
            // in_proj: hb @ in_w^T -> u fp16 (u16) + z bf16 (zy).  N=512, K=128
            gemm_mfma<<<dim3(8, BLTOK / 64), 256, 0, stream>>>(
                hb, DMODEL, inwh + (size_t)s * 512 * 128, 128,
                nullptr, u16, zy, 512, 128, dir, 1);
            // depthwise causal conv + silu: u16 -> ucb fp16
            dwconv_silu<<<16 * 128, 256, 0, stream>>>(
                u16, cw + (size_t)s * 256 * 8, cb + (size_t)s * 256, ucb);
            // x_proj: ucb @ xp_w^T -> dbc (ldc=72).  N=72, K=256
            gemm_mfma<<<dim3(2, BLTOK / 64), 256, 0, stream>>>(
                ucb, DINNER, xpwh + (size_t)s * 72 * 256, 256,
                dbc, nullptr, nullptr, 72, 256, 0, 0);
            // chunked scan
            scan_phase1<<<16 * GCH, 256, 0, stream>>>(
                dbc, ucb, aggh, aggs,
                dtw + (size_t)s * 256 * 8, dtb + (size_t)s * 256,
                alog + (size_t)s * 256 * 32);
            scan_phase2<<<16 * 32, 256, 0, stream>>>(
                aggh, aggs, alog + (size_t)s * 256 * 32);
            scan_phase3<<<16 * GCH, 256, 0, stream>>>(
                dbc, ucb, zy, (_Float16*)zy, aggh,
                dtw + (size_t)s * 256 * 8, dtb + (size_t)s * 256,
                alog + (size_t)s * 256 * 32, dpar + (size_t)s * 256);
            // out_proj: y(fp16, in zy) @ out_w^T -> E16 fp16.  N=128, K=256
            gemm_mfma<<<dim3(2, BLTOK / 64), 256, 0, stream>>>(
                (const _Float16*)zy, DINNER, outwh + (size_t)s * 128 * 256, 256,
                nullptr, E16, nullptr, 128, 256, 0, 2 + dir);
        }
        combine_ln<<<BLTOK, 128, 0, stream>>>(
            E16, h, hb, lng + blk * 128, lnb + blk * 128);
    }

    final_proj<<<BLTOK, 128, 0, stream>>>(h, pw, pb, out);
}

// Round 14
// 4220.789 us; speedup vs baseline: 1.0510x; 1.0510x over previous
//
#include <hip/hip_runtime.h>
#include <hip/hip_bf16.h>
#include <cstdint>
#include <cstddef>

// Problem constants
#define L_SEQ   4096
#define BATCH_N 16
#define BLTOK   (BATCH_N * L_SEQ)   // 65536 tokens
#define DMODEL  128
#define DINNER  256
#define DSTATE  32
#define DTRANK  8

// Scan chunking
#define LC  64                      // chunk length
#define GCH 64                      // chunks per sequence
#define LOG2E 1.44269504088896340736f

typedef _Float16 half8 __attribute__((ext_vector_type(8)));
typedef float    floatx4 __attribute__((ext_vector_type(4)));

#define LDSW 40   // LDS row stride in halves (32 data + 8 pad; 80B = 16B-aligned, 2-way banks = free)

// ---------------------------------------------------------------------------
// Pre-conv (1->128 channels, k=7, same padding) + exact GELU.  Writes fp32 + fp16.
// ---------------------------------------------------------------------------
__global__ __launch_bounds__(128) void pre_conv_gelu(
    const float* __restrict__ x,      // (16,4096,1)
    const float* __restrict__ w,      // (128,1,7)
    const float* __restrict__ bias,   // (128,)
    float* __restrict__ h,            // (BLTOK,128)
    _Float16* __restrict__ hb)        // (BLTOK,128)
{
    int r = blockIdx.x;
    int c = threadIdx.x;
    int b = r >> 12;
    int l = r & 4095;
    float acc = bias[c];
    const float* wp = w + c * 7;
#pragma unroll
    for (int k = 0; k < 7; ++k) {
        int ll = l + k - 3;
        if (ll >= 0 && ll < L_SEQ)
            acc += x[(size_t)(b << 12) + ll] * wp[k];
    }
    float ge = 0.5f * acc * (1.f + erff(acc * 0.70710678118654752f));
    h[(size_t)r * DMODEL + c]  = ge;
    hb[(size_t)r * DMODEL + c] = (_Float16)ge;
}

// ---------------------------------------------------------------------------
// Convert fp32 weights -> fp16 (runs once per launch; deterministic).
// ---------------------------------------------------------------------------
__global__ __launch_bounds__(256) void cvt_weights(
    const float* __restrict__ inw,  _Float16* __restrict__ inwh,   // 12*512*128
    const float* __restrict__ xpw,  _Float16* __restrict__ xpwh,   // 12*72*256
    const float* __restrict__ outw, _Float16* __restrict__ outwh)  // 12*128*256
{
    int i = blockIdx.x * 256 + threadIdx.x;
    if (i < 12 * 512 * 128) inwh[i]  = (_Float16)inw[i];
    if (i < 12 * 72 * 256)  xpwh[i]  = (_Float16)xpw[i];
    if (i < 12 * 128 * 256) outwh[i] = (_Float16)outw[i];
}

// ---------------------------------------------------------------------------
// MFMA fp16 GEMM: C[M,N] = A[M,K] @ W[N,K]^T, fp32 accumulate.
// Epilogue modes:
//   0: x_proj  -> Out[row*72+col] fp32, col<N guarded
//   1: in_proj -> col<256: U16[row*256+col] fp16 (u); col>=256: Zb bf16 (z)
//   2: out_proj fwd -> U16[row*128+col] fp16 (E)
//   3: out_proj bwd -> U16[flip(row)*128+col] = 0.5*(existing + acc), fp16
// ---------------------------------------------------------------------------
__global__ __launch_bounds__(256) void gemm_mfma(
    const _Float16* __restrict__ A, int lda,
    const _Float16* __restrict__ W, int ldw,   // N x ldw, K contiguous
    float* __restrict__ Out,
    _Float16* __restrict__ U16,
    __hip_bfloat16* __restrict__ Zb,
    int N, int K, int rev, int mode)
{
    __shared__ __align__(16) _Float16 As[64 * LDSW];
    __shared__ __align__(16) _Float16 Ws[64 * LDSW];

    int tid  = threadIdx.x;
    int wave = tid >> 6;
    int lane = tid & 63;
    int m0 = blockIdx.y * 64;
    int n0 = blockIdx.x * 64;

    int srow = tid >> 2;
    int skc  = (tid & 3) * 8;

    int garow = m0 + srow;
    if (rev) { int bb = garow >> 12; int ll = garow & 4095; garow = (bb << 12) + (4095 - ll); }
    const _Float16* Aptr = A + (size_t)garow * lda + skc;
    int wrow = n0 + srow;
    bool wok = (wrow < N);
    const _Float16* Wptr = W + (size_t)(wok ? wrow : 0) * ldw + skc;

    int lr = lane & 15;
    int lk = (lane >> 4) * 8;
    int soff = srow * LDSW + skc;
    int aoff = (16 * wave + lr) * LDSW + lk;

    floatx4 acc0 = {0.f, 0.f, 0.f, 0.f};
    floatx4 acc1 = acc0, acc2 = acc0, acc3 = acc0;

    for (int k0 = 0; k0 < K; k0 += 32) {
        half8 av = *(const half8*)(Aptr + k0);
        half8 bv = {};
        if (wok) bv = *(const half8*)(Wptr + k0);
        __syncthreads();
        *(half8*)&As[soff] = av;
        *(half8*)&Ws[soff] = bv;
        __syncthreads();
        half8 af = *(const half8*)&As[aoff];
        half8 b0 = *(const half8*)&Ws[( 0 + lr) * LDSW + lk];
        half8 b1 = *(const half8*)&Ws[(16 + lr) * LDSW + lk];
        half8 b2 = *(const half8*)&Ws[(32 + lr) * LDSW + lk];
        half8 b3 = *(const half8*)&Ws[(48 + lr) * LDSW + lk];
        acc0 = __builtin_amdgcn_mfma_f32_16x16x32_f16(af, b0, acc0, 0, 0, 0);
        acc1 = __builtin_amdgcn_mfma_f32_16x16x32_f16(af, b1, acc1, 0, 0, 0);
        acc2 = __builtin_amdgcn_mfma_f32_16x16x32_f16(af, b2, acc2, 0, 0, 0);
        acc3 = __builtin_amdgcn_mfma_f32_16x16x32_f16(af, b3, acc3, 0, 0, 0);
    }

    int orow = m0 + 16 * wave + (lane >> 4) * 4;
    floatx4 av4[4] = {acc0, acc1, acc2, acc3};
#pragma unroll
    for (int jb = 0; jb < 4; ++jb) {
        int col = n0 + jb * 16 + lr;
#pragma unroll
        for (int r = 0; r < 4; ++r) {
            int row = orow + r;
            float v = av4[jb][r];
            if (mode == 0) {
                if (col < N) Out[(size_t)row * 72 + col] = v;
            } else if (mode == 1) {
                if (col < 256) U16[(size_t)row * 256 + col] = (_Float16)v;
                else Zb[(size_t)row * 256 + (col - 256)] = __float2bfloat16(v);
            } else if (mode == 2) {
                U16[(size_t)row * 128 + col] = (_Float16)v;
            } else {
                int bb = row >> 12, ll = row & 4095;
                size_t o = ((size_t)(bb << 12) + (4095 - ll)) * 128 + col;
                U16[o] = (_Float16)(0.5f * ((float)U16[o] + v));
            }
        }
    }
}

// ---------------------------------------------------------------------------
// Depthwise causal conv (k=8, pad (7,0)) + SiLU, register sliding window.
// ---------------------------------------------------------------------------
__global__ __launch_bounds__(256) void dwconv_silu(
    const _Float16* __restrict__ u,   // (BLTOK,256)
    const float* __restrict__ cw,     // (256,1,8)
    const float* __restrict__ cb,     // (256,)
    _Float16* __restrict__ uc)        // (BLTOK,256)
{
    int b  = blockIdx.x >> 7;
    int lt = blockIdx.x & 127;
    int l0 = lt * 32;
    int d  = threadIdx.x;

    float wv[8];
    const float* wp = cw + d * 8;
#pragma unroll
    for (int k = 0; k < 8; ++k) wv[k] = wp[k];
    float bias = cb[d];

    size_t rowb = (size_t)(b << 12);
    float win[8];
#pragma unroll
    for (int j = 0; j < 7; ++j) {
        int ll = l0 - 7 + j;
        win[j] = (ll >= 0) ? (float)u[(rowb + ll) * DINNER + d] : 0.f;
    }
#pragma unroll
    for (int i = 0; i < 32; ++i) {
        int l = l0 + i;
        win[7] = (float)u[(rowb + l) * DINNER + d];
        float acc = bias;
#pragma unroll
        for (int j = 0; j < 8; ++j) acc += win[j] * wv[j];
        float s = acc / (1.f + __expf(-acc));
        uc[(rowb + l) * DINNER + d] = (_Float16)s;
#pragma unroll
        for (int j = 0; j < 7; ++j) win[j] = win[j + 1];
    }
}

// ---------------------------------------------------------------------------
// Phase 1 (serial local scan, zero-init) — R12 structure (scalar arrays ->
// AGPR backing; NO vector arrays, NO prefetch temps: R8/R10 spilled).
// NEW (R14): also emits y0_t = <h0_t, C_t> + u_t*D (fp16, in-place over the
// consumed u in ucy) and cumS_t (fp16) — enabling a stateless phase 3:
//   h_t = h0_t + exp(a*cumS_t) (.) h_in   [induction proof in journal]
// Aggregates: aggh fp16 h_end, aggs f32 S.
// ---------------------------------------------------------------------------
__global__ __launch_bounds__(256, 4) void scan_phase1(
    const float* __restrict__ dbc,    // (BLTOK,72)
    _Float16* ucy,                    // (BLTOK,256): u in, y0 out (in-place)
    _Float16* __restrict__ cums,      // (BLTOK,256) fp16 cumS
    _Float16* __restrict__ aggh,      // fp16 h_end / h_in
    float* __restrict__ aggs,
    const float* __restrict__ dt_w,
    const float* __restrict__ dt_b,
    const float* __restrict__ a_log,
    const float* __restrict__ Dp)
{
    __shared__ __align__(16) float sh[LC * 72];
    int bg = blockIdx.x;
    int b  = bg >> 6;
    int g  = bg & (GCH - 1);
    int d  = threadIdx.x;

    size_t base = (size_t)b * L_SEQ + (size_t)g * LC;
    {
        const float4* src4 = (const float4*)(dbc + base * 72);
        float4* dst4 = (float4*)sh;
        for (int i = d; i < LC * 18; i += 256) dst4[i] = src4[i];
    }

    const float* wr = dt_w + d * DTRANK;
    float w0 = wr[0], w1 = wr[1], w2 = wr[2], w3 = wr[3];
    float w4 = wr[4], w5 = wr[5], w6 = wr[6], w7 = wr[7];
    float bias = dt_b[d];
    float Dd = Dp[d];

    float al2[32];
    {
        const float4* ar = (const float4*)(a_log + d * DSTATE);
#pragma unroll
        for (int k = 0; k < 8; ++k) {
            float4 v = ar[k];
            al2[4 * k + 0] = -__expf(v.x) * LOG2E;
            al2[4 * k + 1] = -__expf(v.y) * LOG2E;
            al2[4 * k + 2] = -__expf(v.z) * LOG2E;
            al2[4 * k + 3] = -__expf(v.w) * LOG2E;
        }
    }
    __syncthreads();

    float h[32];
#pragma unroll
    for (int n = 0; n < 32; ++n) h[n] = 0.f;
    float S = 0.f;

    for (int t = 0; t < LC; ++t) {
        const float* row = sh + t * 72;
        float4 r0 = *(const float4*)row;
        float4 r1 = *(const float4*)(row + 4);
        float dtr = bias + r0.x * w0 + r0.y * w1 + r0.z * w2 + r0.w * w3
                         + r1.x * w4 + r1.y * w5 + r1.z * w6 + r1.w * w7;
        float dtv = (dtr > 15.f) ? dtr : __logf(1.f + __expf(dtr));
        S += dtv;
        float uv = (float)ucy[(base + t) * DINNER + d];
        float du = dtv * uv;

        float y = 0.f;
#pragma unroll
        for (int n = 0; n < 32; n += 4) {
            float4 Bv = *(const float4*)(row + 8 + n);
            float4 Cv = *(const float4*)(row + 40 + n);
            h[n + 0] = h[n + 0] * __builtin_amdgcn_exp2f(dtv * al2[n + 0]) + du * Bv.x;
            h[n + 1] = h[n + 1] * __builtin_amdgcn_exp2f(dtv * al2[n + 1]) + du * Bv.y;
            h[n + 2] = h[n + 2] * __builtin_amdgcn_exp2f(dtv * al2[n + 2]) + du * Bv.z;
            h[n + 3] = h[n + 3] * __builtin_amdgcn_exp2f(dtv * al2[n + 3]) + du * Bv.w;
            y += h[n + 0] * Cv.x + h[n + 1] * Cv.y
               + h[n + 2] * Cv.z + h[n + 3] * Cv.w;
        }
        ucy[(base + t) * DINNER + d]  = (_Float16)(y + uv * Dd);  // y0 (incl. D-skip)
        cums[(base + t) * DINNER + d] = (_Float16)S;
    }

    size_t ob = ((size_t)(b * GCH + g) * 32) * 256 + d;
#pragma unroll
    for (int n = 0; n < 32; ++n) aggh[ob + (size_t)n * 256] = (_Float16)h[n];
    aggs[(size_t)(b * GCH + g) * 256 + d] = S;
}

// ---------------------------------------------------------------------------
// Phase 2: serial combine across chunks.  P_n = exp(a_n * S_g).  aggh fp16.
// ---------------------------------------------------------------------------
__global__ __launch_bounds__(256) void scan_phase2(
    _Float16* __restrict__ aggh,
    const float* __restrict__ aggs,
    const float* __restrict__ a_log)
{
    int b = blockIdx.x >> 5;
    int n = blockIdx.x & 31;
    int d = threadIdx.x;

    float a = -__expf(a_log[d * DSTATE + n]);
    float hrun = 0.f;
    for (int g = 0; g < GCH; ++g) {
        size_t os = (size_t)(b * GCH + g) * 256 + d;
        size_t oh = ((size_t)(b * GCH + g) * 32 + n) * 256 + d;
        float S  = aggs[os];
        float he = (float)aggh[oh];
        aggh[oh] = (_Float16)hrun;
        hrun = hrun * __expf(a * S) + he;
    }
}

// ---------------------------------------------------------------------------
// Phase 3' (R14): STATELESS parallel correction + gate.
//   y_t = y0_t + sum_n exp(a_n*cumS_t) * h_in[n] * C_t[n];  out = y*silu(z)
// No carried state -> t-iterations independent -> fully pipelineable.
// Only C cols staged in LDS (8 KB).  Scalar arrays (al2, hin) -> AGPRs.
// ---------------------------------------------------------------------------
__global__ __launch_bounds__(256, 4) void scan_corr(
    const float* __restrict__ dbc,        // (BLTOK,72), only C cols used
    const _Float16* __restrict__ y0,      // (BLTOK,256)
    const _Float16* __restrict__ cums,    // (BLTOK,256)
    const __hip_bfloat16* __restrict__ z_in,  // (BLTOK,256)
    _Float16* __restrict__ y_out,         // (BLTOK,256) (same buffer as z_in)
    const _Float16* __restrict__ aggh,    // fp16 h_in
    const float* __restrict__ a_log)
{
    __shared__ __align__(16) float shc[LC * 32];   // C only: 8 KB
    int bg = blockIdx.x;
    int b  = bg >> 6;
    int g  = bg & (GCH - 1);
    int d  = threadIdx.x;

    size_t base = (size_t)b * L_SEQ + (size_t)g * LC;
    {
        // dbc row = 18 float4; C = cols 40..71 = float4 idx 10..17
        const float4* src4 = (const float4*)(dbc + base * 72);
        float4* dst4 = (float4*)shc;
        for (int i = d; i < LC * 8; i += 256) {
            int t = i >> 3, q = i & 7;
            dst4[t * 8 + q] = src4[t * 18 + 10 + q];
        }
    }

    float al2[32];
    {
        const float4* ar = (const float4*)(a_log + d * DSTATE);
#pragma unroll
        for (int k = 0; k < 8; ++k) {
            float4 v = ar[k];
            al2[4 * k + 0] = -__expf(v.x) * LOG2E;
            al2[4 * k + 1] = -__expf(v.y) * LOG2E;
            al2[4 * k + 2] = -__expf(v.z) * LOG2E;
            al2[4 * k + 3] = -__expf(v.w) * LOG2E;
        }
    }

    float hin[32];
    size_t ob = ((size_t)(b * GCH + g) * 32) * 256 + d;
#pragma unroll
    for (int n = 0; n < 32; ++n) hin[n] = (float)aggh[ob + (size_t)n * 256];

    __syncthreads();

    for (int t = 0; t < LC; ++t) {
        size_t idx = (base + t) * DINNER + d;
        float cs  = (float)cums[idx];
        float y0v = (float)y0[idx];
        float zv  = __bfloat162float(z_in[idx]);
        const float* Crow = shc + t * 32;

        float corr = 0.f;
#pragma unroll
        for (int n = 0; n < 32; n += 4) {
            float4 Cv = *(const float4*)(Crow + n);
            corr += __builtin_amdgcn_exp2f(cs * al2[n + 0]) * hin[n + 0] * Cv.x;
            corr += __builtin_amdgcn_exp2f(cs * al2[n + 1]) * hin[n + 1] * Cv.y;
            corr += __builtin_amdgcn_exp2f(cs * al2[n + 2]) * hin[n + 2] * Cv.z;
            corr += __builtin_amdgcn_exp2f(cs * al2[n + 3]) * hin[n + 3] * Cv.w;
        }
        float yv = y0v + corr;
        float sig = 1.f / (1.f + __expf(-zv));
        y_out[idx] = (_Float16)(yv * (zv * sig));
    }
}

// ---------------------------------------------------------------------------
// h = LayerNorm(osum + h); osum fp16.  Writes fp32 h and fp16 hb.
// ---------------------------------------------------------------------------
__global__ __launch_bounds__(128) void combine_ln(
    const _Float16* __restrict__ osum, // (BLTOK,128)
    float* __restrict__ h,             // (BLTOK,128)
    _Float16* __restrict__ hb,         // (BLTOK,128)
    const float* __restrict__ g,
    const float* __restrict__ be)
{
    __shared__ float red[128];
    int r = blockIdx.x;
    int c = threadIdx.x;
    size_t idx = (size_t)r * DMODEL + c;

    float v = (float)osum[idx] + h[idx];

    red[c] = v;
    __syncthreads();
    for (int s = 64; s > 0; s >>= 1) {
        if (c < s) red[c] += red[c + s];
        __syncthreads();
    }
    float mu = red[0] * (1.f / 128.f);
    __syncthreads();
    float dv = v - mu;
    red[c] = dv * dv;
    __syncthreads();
    for (int s = 64; s > 0; s >>= 1) {
        if (c < s) red[c] += red[c + s];
        __syncthreads();
    }
    float var = red[0] * (1.f / 128.f);
    float o = dv * rsqrtf(var + 1e-5f) * g[c] + be[c];
    h[idx]  = o;
    hb[idx] = (_Float16)o;
}

// ---------------------------------------------------------------------------
__global__ __launch_bounds__(128) void final_proj(
    const float* __restrict__ h,
    const float* __restrict__ pw,     // (1,128)
    const float* __restrict__ pb,     // (1,)
    float* __restrict__ out)          // (BLTOK,)
{
    __shared__ float red[128];
    int r = blockIdx.x;
    int c = threadIdx.x;
    red[c] = h[(size_t)r * DMODEL + c] * pw[c];
    __syncthreads();
    for (int s = 64; s > 0; s >>= 1) {
        if (c < s) red[c] += red[c + s];
        __syncthreads();
    }
    if (c == 0) out[r] = red[0] + pb[0];
}

// ---------------------------------------------------------------------------
extern "C" void kernel_launch(void* const* d_in, const int* in_sizes, int n_in,
                              void* d_out, int out_size, void* d_ws, size_t ws_size,
                              hipStream_t stream)
{
    const float* x    = (const float*)d_in[0];
    const float* pcw  = (const float*)d_in[1];
    const float* pcb  = (const float*)d_in[2];
    const float* inw  = (const float*)d_in[3];
    const float* cw   = (const float*)d_in[4];
    const float* cb   = (const float*)d_in[5];
    const float* xpw  = (const float*)d_in[6];
    const float* dtw  = (const float*)d_in[7];
    const float* dtb  = (const float*)d_in[8];
    const float* alog = (const float*)d_in[9];
    const float* dpar = (const float*)d_in[10];
    const float* outw = (const float*)d_in[11];
    const float* lng  = (const float*)d_in[12];
    const float* lnb  = (const float*)d_in[13];
    const float* pw   = (const float*)d_in[14];
    const float* pb   = (const float*)d_in[15];
    float* out = (float*)d_out;

    // Workspace layout (~222 MiB total; 235 MiB proven safe in R2):
    //   h    : BLTOK*128 f32   residual stream
    //   A16  : BLTOK*256 f16   u16 (in_proj->conv), then dbc f32 BLTOK*72
    //                          (x_proj->scan) [disjoint lifetimes; 18.9<33.5MB]
    //   zy   : BLTOK*256 2B    z bf16 (in_proj) -> y fp16 (scan_corr)
    //   ucb  : BLTOK*256 f16   u (conv) -> y0 (phase1, in-place)
    //   hb   : BLTOK*128 f16   fp16 shadow of h
    //   E16  : BLTOK*128 f16   out accumulation
    //   w16  : fp16 weights | aggs f32 | aggh f16 | cums f16
    float* h  = (float*)d_ws;
    _Float16* A16 = (_Float16*)(h + (size_t)BLTOK * 128);
    _Float16* u16 = A16;
    float* dbc = (float*)A16;
    __hip_bfloat16* zy = (__hip_bfloat16*)(A16 + (size_t)BLTOK * 256);
    _Float16* ucb = (_Float16*)((char*)zy + (size_t)BLTOK * 256 * 2);
    _Float16* hb  = ucb + (size_t)BLTOK * 256;
    _Float16* E16 = hb + (size_t)BLTOK * 128;
    _Float16* inwh  = E16 + (size_t)BLTOK * 128;
    _Float16* xpwh  = inwh + (size_t)12 * 512 * 128;
    _Float16* outwh = xpwh + (size_t)12 * 72 * 256;
    float* aggs = (float*)(outwh + (size_t)12 * 128 * 256);    // 1 MB
    _Float16* aggh = (_Float16*)(aggs + (size_t)16 * GCH * 256); // 16.8 MB
    _Float16* cums = aggh + (size_t)16 * GCH * 32 * 256;       // 33.5 MB

    cvt_weights<<<(12 * 512 * 128 + 255) / 256, 256, 0, stream>>>(
        inw, inwh, xpw, xpwh, outw, outwh);
    pre_conv_gelu<<<BLTOK, 128, 0, stream>>>(x, pcw, pcb, h, hb);

    for (int blk = 0; blk < 6; ++blk) {
        for (int dir = 0; dir < 2; ++dir) {
            int s = blk * 2 + dir;
            // in_proj: hb @ in_w^T -> u fp16 (u16) + z bf16 (zy).  N=512, K=128
            gemm_mfma<<<dim3(8, BLTOK / 64), 256, 0, stream>>>(
                hb, DMODEL, inwh + (size_t)s * 512 * 128, 128,
                nullptr, u16, zy, 512, 128, dir, 1);
            // depthwise causal conv + silu: u16 -> ucb fp16
            dwconv_silu<<<16 * 128, 256, 0, stream>>>(
                u16, cw + (size_t)s * 256 * 8, cb + (size_t)s * 256, ucb);
            // x_proj: ucb @ xp_w^T -> dbc (ldc=72).  N=72, K=256
            gemm_mfma<<<dim3(2, BLTOK / 64), 256, 0, stream>>>(
                ucb, DINNER, xpwh + (size_t)s * 72 * 256, 256,
                dbc, nullptr, nullptr, 72, 256, 0, 0);
            // chunked scan: phase1 (serial local, emits y0+cumS+aggregates)
            scan_phase1<<<16 * GCH, 256, 0, stream>>>(
                dbc, ucb, cums, aggh, aggs,
                dtw + (size_t)s * 256 * 8, dtb + (size_t)s * 256,
                alog + (size_t)s * 256 * 32, dpar + (size_t)s * 256);
            // phase2: chunk combine (aggh fp16 -> h_in)
            scan_phase2<<<16 * 32, 256, 0, stream>>>(
                aggh, aggs, alog + (size_t)s * 256 * 32);
            // phase3': stateless parallel correction + gate -> y fp16 in zy
            scan_corr<<<16 * GCH, 256, 0, stream>>>(
                dbc, ucb, cums, zy, (_Float16*)zy, aggh,
                alog + (size_t)s * 256 * 32);
            // out_proj: y(fp16, in zy) @ out_w^T -> E16 fp16.  N=128, K=256
            gemm_mfma<<<dim3(2, BLTOK / 64), 256, 0, stream>>>(
                (const _Float16*)zy, DINNER, outwh + (size_t)s * 128 * 256, 256,
                nullptr, E16, nullptr, 128, 256, 0, 2 + dir);
        }
        combine_ln<<<BLTOK, 128, 0, stream>>>(
            E16, h, hb, lng + blk * 128, lnb + blk * 128);
    }

    final_proj<<<BLTOK, 128, 0, stream>>>(h, pw, pb, out);
}

// Round 16
// 4107.838 us; speedup vs baseline: 1.0799x; 1.0275x over previous
//
#include <hip/hip_runtime.h>
#include <hip/hip_bf16.h>
#include <cstdint>
#include <cstddef>

// Problem constants
#define L_SEQ   4096
#define BATCH_N 16
#define BLTOK   (BATCH_N * L_SEQ)   // 65536 tokens
#define DMODEL  128
#define DINNER  256
#define DSTATE  32
#define DTRANK  8

// Scan chunking
#define LC  64                      // chunk length
#define GCH 64                      // chunks per sequence
#define LOG2E 1.44269504088896340736f

typedef _Float16 half8 __attribute__((ext_vector_type(8)));
typedef float    floatx4 __attribute__((ext_vector_type(4)));

#define LDSW 40   // LDS row stride in halves (32 data + 8 pad; 80B = 16B-aligned, 2-way banks = free)

// ---------------------------------------------------------------------------
// Pre-conv (1->128 channels, k=7, same padding) + exact GELU.  Writes fp32 + fp16.
// ---------------------------------------------------------------------------
__global__ __launch_bounds__(128) void pre_conv_gelu(
    const float* __restrict__ x,      // (16,4096,1)
    const float* __restrict__ w,      // (128,1,7)
    const float* __restrict__ bias,   // (128,)
    float* __restrict__ h,            // (BLTOK,128)
    _Float16* __restrict__ hb)        // (BLTOK,128)
{
    int r = blockIdx.x;
    int c = threadIdx.x;
    int b = r >> 12;
    int l = r & 4095;
    float acc = bias[c];
    const float* wp = w + c * 7;
#pragma unroll
    for (int k = 0; k < 7; ++k) {
        int ll = l + k - 3;
        if (ll >= 0 && ll < L_SEQ)
            acc += x[(size_t)(b << 12) + ll] * wp[k];
    }
    float ge = 0.5f * acc * (1.f + erff(acc * 0.70710678118654752f));
    h[(size_t)r * DMODEL + c]  = ge;
    hb[(size_t)r * DMODEL + c] = (_Float16)ge;
}

// ---------------------------------------------------------------------------
// Convert fp32 weights -> fp16 (runs once per launch; deterministic).
// ---------------------------------------------------------------------------
__global__ __launch_bounds__(256) void cvt_weights(
    const float* __restrict__ inw,  _Float16* __restrict__ inwh,   // 12*512*128
    const float* __restrict__ xpw,  _Float16* __restrict__ xpwh,   // 12*72*256
    const float* __restrict__ outw, _Float16* __restrict__ outwh)  // 12*128*256
{
    int i = blockIdx.x * 256 + threadIdx.x;
    if (i < 12 * 512 * 128) inwh[i]  = (_Float16)inw[i];
    if (i < 12 * 72 * 256)  xpwh[i]  = (_Float16)xpw[i];
    if (i < 12 * 128 * 256) outwh[i] = (_Float16)outw[i];
}

// ---------------------------------------------------------------------------
// MFMA fp16 GEMM: C[M,N] = A[M,K] @ W[N,K]^T, fp32 accumulate.  (R14-proven)
// Epilogue modes:
//   0: x_proj  -> Out[row*72+col] fp32, col<N guarded
//   1: in_proj -> col<256: U16[row*256+col] fp16 (u); col>=256: Zb bf16 (z)
//   2: out_proj fwd -> U16[row*128+col] fp16 (E)
//   3: out_proj bwd -> U16[flip(row)*128+col] = 0.5*(existing + acc), fp16
// ---------------------------------------------------------------------------
__global__ __launch_bounds__(256) void gemm_mfma(
    const _Float16* __restrict__ A, int lda,
    const _Float16* __restrict__ W, int ldw,   // N x ldw, K contiguous
    float* __restrict__ Out,
    _Float16* __restrict__ U16,
    __hip_bfloat16* __restrict__ Zb,
    int N, int K, int rev, int mode)
{
    __shared__ __align__(16) _Float16 As[64 * LDSW];
    __shared__ __align__(16) _Float16 Ws[64 * LDSW];

    int tid  = threadIdx.x;
    int wave = tid >> 6;
    int lane = tid & 63;
    int m0 = blockIdx.y * 64;
    int n0 = blockIdx.x * 64;

    int srow = tid >> 2;
    int skc  = (tid & 3) * 8;

    int garow = m0 + srow;
    if (rev) { int bb = garow >> 12; int ll = garow & 4095; garow = (bb << 12) + (4095 - ll); }
    const _Float16* Aptr = A + (size_t)garow * lda + skc;
    int wrow = n0 + srow;
    bool wok = (wrow < N);
    const _Float16* Wptr = W + (size_t)(wok ? wrow : 0) * ldw + skc;

    int lr = lane & 15;
    int lk = (lane >> 4) * 8;
    int soff = srow * LDSW + skc;
    int aoff = (16 * wave + lr) * LDSW + lk;

    floatx4 acc0 = {0.f, 0.f, 0.f, 0.f};
    floatx4 acc1 = acc0, acc2 = acc0, acc3 = acc0;

    for (int k0 = 0; k0 < K; k0 += 32) {
        half8 av = *(const half8*)(Aptr + k0);
        half8 bv = {};
        if (wok) bv = *(const half8*)(Wptr + k0);
        __syncthreads();
        *(half8*)&As[soff] = av;
        *(half8*)&Ws[soff] = bv;
        __syncthreads();
        half8 af = *(const half8*)&As[aoff];
        half8 b0 = *(const half8*)&Ws[( 0 + lr) * LDSW + lk];
        half8 b1 = *(const half8*)&Ws[(16 + lr) * LDSW + lk];
        half8 b2 = *(const half8*)&Ws[(32 + lr) * LDSW + lk];
        half8 b3 = *(const half8*)&Ws[(48 + lr) * LDSW + lk];
        acc0 = __builtin_amdgcn_mfma_f32_16x16x32_f16(af, b0, acc0, 0, 0, 0);
        acc1 = __builtin_amdgcn_mfma_f32_16x16x32_f16(af, b1, acc1, 0, 0, 0);
        acc2 = __builtin_amdgcn_mfma_f32_16x16x32_f16(af, b2, acc2, 0, 0, 0);
        acc3 = __builtin_amdgcn_mfma_f32_16x16x32_f16(af, b3, acc3, 0, 0, 0);
    }

    int orow = m0 + 16 * wave + (lane >> 4) * 4;
    floatx4 av4[4] = {acc0, acc1, acc2, acc3};
#pragma unroll
    for (int jb = 0; jb < 4; ++jb) {
        int col = n0 + jb * 16 + lr;
#pragma unroll
        for (int r = 0; r < 4; ++r) {
            int row = orow + r;
            float v = av4[jb][r];
            if (mode == 0) {
                if (col < N) Out[(size_t)row * 72 + col] = v;
            } else if (mode == 1) {
                if (col < 256) U16[(size_t)row * 256 + col] = (_Float16)v;
                else Zb[(size_t)row * 256 + (col - 256)] = __float2bfloat16(v);
            } else if (mode == 2) {
                U16[(size_t)row * 128 + col] = (_Float16)v;
            } else {
                int bb = row >> 12, ll = row & 4095;
                size_t o = ((size_t)(bb << 12) + (4095 - ll)) * 128 + col;
                U16[o] = (_Float16)(0.5f * ((float)U16[o] + v));
            }
        }
    }
}

// ---------------------------------------------------------------------------
// Depthwise causal conv (k=8, pad (7,0)) + SiLU, register sliding window.
// ---------------------------------------------------------------------------
__global__ __launch_bounds__(256) void dwconv_silu(
    const _Float16* __restrict__ u,   // (BLTOK,256)
    const float* __restrict__ cw,     // (256,1,8)
    const float* __restrict__ cb,     // (256,)
    _Float16* __restrict__ uc)        // (BLTOK,256)
{
    int b  = blockIdx.x >> 7;
    int lt = blockIdx.x & 127;
    int l0 = lt * 32;
    int d  = threadIdx.x;

    float wv[8];
    const float* wp = cw + d * 8;
#pragma unroll
    for (int k = 0; k < 8; ++k) wv[k] = wp[k];
    float bias = cb[d];

    size_t rowb = (size_t)(b << 12);
    float win[8];
#pragma unroll
    for (int j = 0; j < 7; ++j) {
        int ll = l0 - 7 + j;
        win[j] = (ll >= 0) ? (float)u[(rowb + ll) * DINNER + d] : 0.f;
    }
#pragma unroll
    for (int i = 0; i < 32; ++i) {
        int l = l0 + i;
        win[7] = (float)u[(rowb + l) * DINNER + d];
        float acc = bias;
#pragma unroll
        for (int j = 0; j < 8; ++j) acc += win[j] * wv[j];
        float s = acc / (1.f + __expf(-acc));
        uc[(rowb + l) * DINNER + d] = (_Float16)s;
#pragma unroll
        for (int j = 0; j < 7; ++j) win[j] = win[j + 1];
    }
}

// ---------------------------------------------------------------------------
// Phase 1 (serial local scan, zero-init) — scalar arrays -> AGPR backing
// (R7/R9 lesson); emits y0 (in-place over u), cumS fp16, and aggregates.
// ---------------------------------------------------------------------------
__global__ __launch_bounds__(256, 4) void scan_phase1(
    const float* __restrict__ dbc,    // (BLTOK,72)
    _Float16* ucy,                    // (BLTOK,256): u in, y0 out (in-place)
    _Float16* __restrict__ cums,      // (BLTOK,256) fp16 cumS
    _Float16* __restrict__ aggh,      // fp16 h_end / h_in
    float* __restrict__ aggs,
    const float* __restrict__ dt_w,
    const float* __restrict__ dt_b,
    const float* __restrict__ a_log,
    const float* __restrict__ Dp)
{
    __shared__ __align__(16) float sh[LC * 72];
    int bg = blockIdx.x;
    int b  = bg >> 6;
    int g  = bg & (GCH - 1);
    int d  = threadIdx.x;

    size_t base = (size_t)b * L_SEQ + (size_t)g * LC;
    {
        const float4* src4 = (const float4*)(dbc + base * 72);
        float4* dst4 = (float4*)sh;
        for (int i = d; i < LC * 18; i += 256) dst4[i] = src4[i];
    }

    const float* wr = dt_w + d * DTRANK;
    float w0 = wr[0], w1 = wr[1], w2 = wr[2], w3 = wr[3];
    float w4 = wr[4], w5 = wr[5], w6 = wr[6], w7 = wr[7];
    float bias = dt_b[d];
    float Dd = Dp[d];

    float al2[32];
    {
        const float4* ar = (const float4*)(a_log + d * DSTATE);
#pragma unroll
        for (int k = 0; k < 8; ++k) {
            float4 v = ar[k];
            al2[4 * k + 0] = -__expf(v.x) * LOG2E;
            al2[4 * k + 1] = -__expf(v.y) * LOG2E;
            al2[4 * k + 2] = -__expf(v.z) * LOG2E;
            al2[4 * k + 3] = -__expf(v.w) * LOG2E;
        }
    }
    __syncthreads();

    float h[32];
#pragma unroll
    for (int n = 0; n < 32; ++n) h[n] = 0.f;
    float S = 0.f;

    for (int t = 0; t < LC; ++t) {
        const float* row = sh + t * 72;
        float4 r0 = *(const float4*)row;
        float4 r1 = *(const float4*)(row + 4);
        float dtr = bias + r0.x * w0 + r0.y * w1 + r0.z * w2 + r0.w * w3
                         + r1.x * w4 + r1.y * w5 + r1.z * w6 + r1.w * w7;
        float dtv = (dtr > 15.f) ? dtr : __logf(1.f + __expf(dtr));
        S += dtv;
        float uv = (float)ucy[(base + t) * DINNER + d];
        float du = dtv * uv;

        float y = 0.f;
#pragma unroll
        for (int n = 0; n < 32; n += 4) {
            float4 Bv = *(const float4*)(row + 8 + n);
            float4 Cv = *(const float4*)(row + 40 + n);
            h[n + 0] = h[n + 0] * __builtin_amdgcn_exp2f(dtv * al2[n + 0]) + du * Bv.x;
            h[n + 1] = h[n + 1] * __builtin_amdgcn_exp2f(dtv * al2[n + 1]) + du * Bv.y;
            h[n + 2] = h[n + 2] * __builtin_amdgcn_exp2f(dtv * al2[n + 2]) + du * Bv.z;
            h[n + 3] = h[n + 3] * __builtin_amdgcn_exp2f(dtv * al2[n + 3]) + du * Bv.w;
            y += h[n + 0] * Cv.x + h[n + 1] * Cv.y
               + h[n + 2] * Cv.z + h[n + 3] * Cv.w;
        }
        ucy[(base + t) * DINNER + d]  = (_Float16)(y + uv * Dd);  // y0 (incl. D-skip)
        cums[(base + t) * DINNER + d] = (_Float16)S;
    }

    size_t ob = ((size_t)(b * GCH + g) * 32) * 256 + d;
#pragma unroll
    for (int n = 0; n < 32; ++n) aggh[ob + (size_t)n * 256] = (_Float16)h[n];
    aggs[(size_t)(b * GCH + g) * 256 + d] = S;
}

// ---------------------------------------------------------------------------
// Phase 2: serial combine across chunks.  P_n = exp(a_n * S_g).  aggh fp16.
// ---------------------------------------------------------------------------
__global__ __launch_bounds__(256) void scan_phase2(
    _Float16* __restrict__ aggh,
    const float* __restrict__ aggs,
    const float* __restrict__ a_log)
{
    int b = blockIdx.x >> 5;
    int n = blockIdx.x & 31;
    int d = threadIdx.x;

    float a = -__expf(a_log[d * DSTATE + n]);
    float hrun = 0.f;
    for (int g = 0; g < GCH; ++g) {
        size_t os = (size_t)(b * GCH + g) * 256 + d;
        size_t oh = ((size_t)(b * GCH + g) * 32 + n) * 256 + d;
        float S  = aggs[os];
        float he = (float)aggh[oh];
        aggh[oh] = (_Float16)hrun;
        hrun = hrun * __expf(a * S) + he;
    }
}

// ---------------------------------------------------------------------------
// Phase 3': STATELESS parallel correction + gate.
//   y_t = y0_t + sum_n exp(a_n*cumS_t) * h_in[n] * C_t[n];  out = y*silu(z)
// ---------------------------------------------------------------------------
__global__ __launch_bounds__(256, 4) void scan_corr(
    const float* __restrict__ dbc,        // (BLTOK,72), only C cols used
    const _Float16* __restrict__ y0,      // (BLTOK,256)
    const _Float16* __restrict__ cums,    // (BLTOK,256)
    const __hip_bfloat16* __restrict__ z_in,  // (BLTOK,256)
    _Float16* __restrict__ y_out,         // (BLTOK,256) (same buffer as z_in)
    const _Float16* __restrict__ aggh,    // fp16 h_in
    const float* __restrict__ a_log)
{
    __shared__ __align__(16) float shc[LC * 32];   // C only: 8 KB
    int bg = blockIdx.x;
    int b  = bg >> 6;
    int g  = bg & (GCH - 1);
    int d  = threadIdx.x;

    size_t base = (size_t)b * L_SEQ + (size_t)g * LC;
    {
        const float4* src4 = (const float4*)(dbc + base * 72);
        float4* dst4 = (float4*)shc;
        for (int i = d; i < LC * 8; i += 256) {
            int t = i >> 3, q = i & 7;
            dst4[t * 8 + q] = src4[t * 18 + 10 + q];
        }
    }

    float al2[32];
    {
        const float4* ar = (const float4*)(a_log + d * DSTATE);
#pragma unroll
        for (int k = 0; k < 8; ++k) {
            float4 v = ar[k];
            al2[4 * k + 0] = -__expf(v.x) * LOG2E;
            al2[4 * k + 1] = -__expf(v.y) * LOG2E;
            al2[4 * k + 2] = -__expf(v.z) * LOG2E;
            al2[4 * k + 3] = -__expf(v.w) * LOG2E;
        }
    }

    float hin[32];
    size_t ob = ((size_t)(b * GCH + g) * 32) * 256 + d;
#pragma unroll
    for (int n = 0; n < 32; ++n) hin[n] = (float)aggh[ob + (size_t)n * 256];

    __syncthreads();

    for (int t = 0; t < LC; ++t) {
        size_t idx = (base + t) * DINNER + d;
        float cs  = (float)cums[idx];
        float y0v = (float)y0[idx];
        float zv  = __bfloat162float(z_in[idx]);
        const float* Crow = shc + t * 32;

        float corr = 0.f;
#pragma unroll
        for (int n = 0; n < 32; n += 4) {
            float4 Cv = *(const float4*)(Crow + n);
            corr += __builtin_amdgcn_exp2f(cs * al2[n + 0]) * hin[n + 0] * Cv.x;
            corr += __builtin_amdgcn_exp2f(cs * al2[n + 1]) * hin[n + 1] * Cv.y;
            corr += __builtin_amdgcn_exp2f(cs * al2[n + 2]) * hin[n + 2] * Cv.z;
            corr += __builtin_amdgcn_exp2f(cs * al2[n + 3]) * hin[n + 3] * Cv.w;
        }
        float yv = y0v + corr;
        float sig = 1.f / (1.f + __expf(-zv));
        y_out[idx] = (_Float16)(yv * (zv * sig));
    }
}

// ---------------------------------------------------------------------------
// Wave-per-row combine + LayerNorm (R16): one 64-lane wave owns one LN row
// (2 channels/lane), pure shuffle reductions — no LDS, no __syncthreads.
// 4 rows per 256-thread block.  When last!=0, also fuses the final
// projection: out[row] = dot(LN_out, pw) + pb (third butterfly).
// ---------------------------------------------------------------------------
__global__ __launch_bounds__(256) void combine_ln_wave(
    const _Float16* __restrict__ osum, // (BLTOK,128) 0.5*(f+b)
    float* __restrict__ h,             // (BLTOK,128) residual in / LN out
    _Float16* __restrict__ hb,         // (BLTOK,128) fp16 shadow out
    const float* __restrict__ g,
    const float* __restrict__ be,
    const float* __restrict__ pw,      // (128,) final proj weights
    const float* __restrict__ pb,      // (1,)
    float* __restrict__ out,           // (BLTOK,) final output
    int last)
{
    int wave = threadIdx.x >> 6;
    int lane = threadIdx.x & 63;
    int row  = blockIdx.x * 4 + wave;
    int c0   = lane * 2;
    size_t rb = (size_t)row * 128 + c0;

    float2 hv = *(const float2*)(h + rb);
    float v0 = (float)osum[rb]     + hv.x;
    float v1 = (float)osum[rb + 1] + hv.y;

    float s = v0 + v1;
#pragma unroll
    for (int off = 1; off < 64; off <<= 1) s += __shfl_xor(s, off);
    float mu = s * (1.f / 128.f);
    float d0 = v0 - mu, d1 = v1 - mu;
    float s2 = d0 * d0 + d1 * d1;
#pragma unroll
    for (int off = 1; off < 64; off <<= 1) s2 += __shfl_xor(s2, off);
    float iv = rsqrtf(s2 * (1.f / 128.f) + 1e-5f);

    float o0 = d0 * iv * g[c0]     + be[c0];
    float o1 = d1 * iv * g[c0 + 1] + be[c0 + 1];
    *(float2*)(h + rb) = make_float2(o0, o1);
    hb[rb]     = (_Float16)o0;
    hb[rb + 1] = (_Float16)o1;

    if (last) {
        float acc = o0 * pw[c0] + o1 * pw[c0 + 1];
#pragma unroll
        for (int off = 1; off < 64; off <<= 1) acc += __shfl_xor(acc, off);
        if (lane == 0) out[row] = acc + pb[0];
    }
}

// ---------------------------------------------------------------------------
extern "C" void kernel_launch(void* const* d_in, const int* in_sizes, int n_in,
                              void* d_out, int out_size, void* d_ws, size_t ws_size,
                              hipStream_t stream)
{
    const float* x    = (const float*)d_in[0];
    const float* pcw  = (const float*)d_in[1];
    const float* pcb  = (const float*)d_in[2];
    const float* inw  = (const float*)d_in[3];
    const float* cw   = (const float*)d_in[4];
    const float* cb   = (const float*)d_in[5];
    const float* xpw  = (const float*)d_in[6];
    const float* dtw  = (const float*)d_in[7];
    const float* dtb  = (const float*)d_in[8];
    const float* alog = (const float*)d_in[9];
    const float* dpar = (const float*)d_in[10];
    const float* outw = (const float*)d_in[11];
    const float* lng  = (const float*)d_in[12];
    const float* lnb  = (const float*)d_in[13];
    const float* pw   = (const float*)d_in[14];
    const float* pb   = (const float*)d_in[15];
    float* out = (float*)d_out;

    // Workspace layout (~222 MiB; 235 MiB proven safe in R2):
    float* h  = (float*)d_ws;
    _Float16* A16 = (_Float16*)(h + (size_t)BLTOK * 128);
    _Float16* u16 = A16;
    float* dbc = (float*)A16;
    __hip_bfloat16* zy = (__hip_bfloat16*)(A16 + (size_t)BLTOK * 256);
    _Float16* ucb = (_Float16*)((char*)zy + (size_t)BLTOK * 256 * 2);
    _Float16* hb  = ucb + (size_t)BLTOK * 256;
    _Float16* E16 = hb + (size_t)BLTOK * 128;
    _Float16* inwh  = E16 + (size_t)BLTOK * 128;
    _Float16* xpwh  = inwh + (size_t)12 * 512 * 128;
    _Float16* outwh = xpwh + (size_t)12 * 72 * 256;
    float* aggs = (float*)(outwh + (size_t)12 * 128 * 256);    // 1 MB
    _Float16* aggh = (_Float16*)(aggs + (size_t)16 * GCH * 256); // 16.8 MB
    _Float16* cums = aggh + (size_t)16 * GCH * 32 * 256;       // 33.5 MB

    cvt_weights<<<(12 * 512 * 128 + 255) / 256, 256, 0, stream>>>(
        inw, inwh, xpw, xpwh, outw, outwh);
    pre_conv_gelu<<<BLTOK, 128, 0, stream>>>(x, pcw, pcb, h, hb);

    for (int blk = 0; blk < 6; ++blk) {
        for (int dir = 0; dir < 2; ++dir) {
            int s = blk * 2 + dir;
            // in_proj: hb @ in_w^T -> u fp16 (u16) + z bf16 (zy).  N=512, K=128
            gemm_mfma<<<dim3(8, BLTOK / 64), 256, 0, stream>>>(
                hb, DMODEL, inwh + (size_t)s * 512 * 128, 128,
                nullptr, u16, zy, 512, 128, dir, 1);
            // depthwise causal conv + silu: u16 -> ucb fp16
            dwconv_silu<<<16 * 128, 256, 0, stream>>>(
                u16, cw + (size_t)s * 256 * 8, cb + (size_t)s * 256, ucb);
            // x_proj: ucb @ xp_w^T -> dbc (ldc=72).  N=72, K=256
            gemm_mfma<<<dim3(2, BLTOK / 64), 256, 0, stream>>>(
                ucb, DINNER, xpwh + (size_t)s * 72 * 256, 256,
                dbc, nullptr, nullptr, 72, 256, 0, 0);
            // chunked scan: phase1 (serial local, emits y0+cumS+aggregates)
            scan_phase1<<<16 * GCH, 256, 0, stream>>>(
                dbc, ucb, cums, aggh, aggs,
                dtw + (size_t)s * 256 * 8, dtb + (size_t)s * 256,
                alog + (size_t)s * 256 * 32, dpar + (size_t)s * 256);
            // phase2: chunk combine (aggh fp16 -> h_in)
            scan_phase2<<<16 * 32, 256, 0, stream>>>(
                aggh, aggs, alog + (size_t)s * 256 * 32);
            // phase3': stateless parallel correction + gate -> y fp16 in zy
            scan_corr<<<16 * GCH, 256, 0, stream>>>(
                dbc, ucb, cums, zy, (_Float16*)zy, aggh,
                alog + (size_t)s * 256 * 32);
            // out_proj: fwd -> E16 (mode 2); bwd -> flip-RMW E16 (mode 3)
            gemm_mfma<<<dim3(2, BLTOK / 64), 256, 0, stream>>>(
                (const _Float16*)zy, DINNER, outwh + (size_t)s * 128 * 256, 256,
                nullptr, E16, nullptr, 128, 256, 0, 2 + dir);
        }
        // combine + residual + LayerNorm (wave-per-row, no barriers);
        // blk==5 also fuses the final projection into d_out.
        combine_ln_wave<<<BLTOK / 4, 256, 0, stream>>>(
            E16, h, hb, lng + blk * 128, lnb + blk * 128,
            pw, pb, out, (blk == 5) ? 1 : 0);
    }
}